// Round 12
// baseline (413.138 us; speedup 1.0000x reference)
//
#include <hip/hip_runtime.h>

#define OBS   32
#define NC    512
#define CD    16
#define HD    256
#define BATCH 8192
#define EPS   4e-3f

typedef unsigned short u16;
typedef unsigned int   u32;
typedef __attribute__((ext_vector_type(8))) short bf16x8;   // 8 bf16 = 4 VGPR
typedef __attribute__((ext_vector_type(4))) float f32x4;

__device__ __forceinline__ short f2bf(float x) {            // fp32 -> bf16 RNE
    union { float f; u32 u; } v; v.f = x;
    u32 r = (v.u + 0x7fffu + ((v.u >> 16) & 1u)) >> 16;
    return (short)r;
}
__device__ __forceinline__ float bf2f(short s) {
    union { u32 u; float f; } v; v.u = ((u32)(u16)s) << 16; return v.f;
}
// rounded-to-bf16 word (bf16 result in HIGH 16 bits) — bit-identical to f2bf
__device__ __forceinline__ u32 rneu(float x) {
    union { float f; u32 u; } v; v.f = x;
    return v.u + 0x7fffu + ((v.u >> 16) & 1u);
}
// float value of the bf16 in the high 16 bits of r (1 AND) == bf2f(f2bf(x))
__device__ __forceinline__ float maskf(u32 r) {
    union { u32 u; float f; } v; v.u = r & 0xffff0000u; return v.f;
}

// ---------------------------------------------------------------------------
// Kernel 0 (prep): norms + fcnt; W1 split hi/lo in B-frag chunk order;
// W2t split (stride 264); codebook B-frags; W0m = W0[1+m] + b0 fold.
// ---------------------------------------------------------------------------
__global__ void prep_kernel(const float* __restrict__ cb,
                            const float* __restrict__ W1,
                            const float* __restrict__ W2,
                            const float* __restrict__ W0,
                            const float* __restrict__ B0,
                            float* __restrict__ n32, double* __restrict__ n64,
                            int* __restrict__ fcnt,
                            u16* __restrict__ wsW1, u16* __restrict__ wsW2,
                            u16* __restrict__ wsCB, float* __restrict__ w0m) {
    const int b = blockIdx.x, t = threadIdx.x;
    if (b == 0) {
        if (t == 0) *fcnt = 0;
        #pragma unroll
        for (int h = 0; h < 2; ++h) {
            int c = t + h * 256;
            const float* r = cb + c * CD;
            float s32 = 0.f; double s64 = 0.0;
            #pragma unroll
            for (int j = 0; j < CD; ++j) {
                float v = r[j];
                s32 = fmaf(v, v, s32);
                s64 = fma((double)v, (double)v, s64);
            }
            n32[c] = s32; n64[c] = s64;
        }
    } else if (b <= 256) {
        int e = (b - 1) * 256 + t;          // e = k*256 + n
        int k = e >> 8, n = e & 255;
        float w = W1[k * 256 + n];
        short hi = f2bf(w);
        short lo = f2bf(w - bf2f(hi));
        int s = k >> 5, koff = k & 31;
        wsW1[s * 16384 + n * 32 + koff]        = (u16)hi;
        wsW1[s * 16384 + 8192 + n * 32 + koff] = (u16)lo;
    } else if (b == 257) {                   // W2 (4096 elems)
        #pragma unroll
        for (int i = 0; i < 16; ++i) {
            int e = t * 16 + i;              // e = k*16 + n
            int k = e >> 4, n = e & 15;
            float w = W2[k * CD + n];
            short hi = f2bf(w);
            short lo = f2bf(w - bf2f(hi));
            wsW2[n * 264 + k]        = (u16)hi;
            wsW2[4224 + n * 264 + k] = (u16)lo;
        }
    } else if (b == 258) {                   // codebook B-frags
        #pragma unroll
        for (int i = 0; i < 8; ++i) {
            int sl = t * 8 + i;              // (tile, lane) slot, 2048 total
            int tile = sl >> 6, l = sl & 63;
            int n  = tile * 16 + (l & 15);
            int kb = ((l >> 4) & 1) * 8;
            u16* dh = wsCB + tile * 1024 + l * 8;
            u16* dl = dh + 512;
            #pragma unroll
            for (int j = 0; j < 8; ++j) {
                float w = cb[n * CD + kb + j];
                short hi = f2bf(w);
                dh[j] = (u16)hi;
                dl[j] = (u16)f2bf(w - bf2f(hi));
            }
        }
    } else {                                 // b == 259: W0m = W0[1+m] + b0
        #pragma unroll
        for (int m = 0; m < OBS; ++m)
            w0m[m * HD + t] = W0[(1 + m) * HD + t] + B0[t];
    }
}

// ---------------------------------------------------------------------------
// Kernel 1: MFMA encoder — TWO batch rows (64 tokens) per block, 256 thr.
// Register prefetch of ALL global operands (phase-B W1 dbuf, phase-C W2
// dbuf, phase-D codebook hoist). Phase A packs via rneu bitops (bit-identical
// to f2bf). Quad-reduce drops the index tie-break: ties imply d2==d1 < EPS
// -> token flagged -> fp64 fixup supplies the exact lowest-index argmin.
// ---------------------------------------------------------------------------
__global__ void __launch_bounds__(256) encoder_kernel(
    const float* __restrict__ obs,
    const float* __restrict__ W0, const float* __restrict__ w0m,
    const float* __restrict__ B1, const float* __restrict__ B2,
    const u16* __restrict__ wsW1, const u16* __restrict__ wsW2,
    const u16* __restrict__ wsCB, const float* __restrict__ n32,
    int* __restrict__ idxbuf, int* __restrict__ fcnt, int* __restrict__ flist)
{
    __shared__ __align__(16) u16  hH[64 * 264];    // 33792 B  hi plane
    __shared__ __align__(16) u16  hL[64 * 264];    // 33792 B  lo plane
    __shared__ __align__(16) u16  embsH[64 * 24];  //  3072 B  emb hi plane
    __shared__ __align__(16) u16  embsL[64 * 24];  //  3072 B  emb lo plane
    __shared__ float redD[4][64][2];               //  2048 B
    __shared__ int   redI[4][64];                  //  1024 B  (76800 B -> 2 blk/CU)

    const int tid = threadIdx.x;
    const int blk = blockIdx.x;
    const int l   = tid & 63;
    const int wv  = tid >> 6;
    const int q   = l >> 4;          // quad 0..3
    const int ln  = l & 15;
    const int nq  = wv;              // N-quarter (cols nq*64 .. +63)

    // ---- phase A (ALL waves): token m = tid>>2 (0..63), 4 lanes/token ----
    {
        const int m = tid >> 2;          // 0..63  (row m>>5, tok m&31)
        const int p = tid & 3;           // k-chunk lane
        const float x = obs[blk * 64 + m];
        const float* W0m = w0m + (m & 31) * HD;
        #pragma unroll
        for (int s = 0; s < 8; ++s) {
            const int k0 = s * 32 + p * 8;
            float w0v[8], wmv[8];
            *(float4*)&w0v[0] = *(const float4*)(W0 + k0);
            *(float4*)&w0v[4] = *(const float4*)(W0 + k0 + 4);
            *(float4*)&wmv[0] = *(const float4*)(W0m + k0);
            *(float4*)&wmv[4] = *(const float4*)(W0m + k0 + 4);
            u32 hiP[4], loP[4];
            #pragma unroll
            for (int jp = 0; jp < 4; ++jp) {
                float ha = fmaxf(fmaf(x, w0v[2 * jp],     wmv[2 * jp]),     0.f);
                float hb = fmaxf(fmaf(x, w0v[2 * jp + 1], wmv[2 * jp + 1]), 0.f);
                u32 ra = rneu(ha), rb = rneu(hb);
                hiP[jp] = (rb & 0xffff0000u) | (ra >> 16);
                u32 la = rneu(ha - maskf(ra)), lb = rneu(hb - maskf(rb));
                loP[jp] = (lb & 0xffff0000u) | (la >> 16);
            }
            *(uint4*)&hH[m * 264 + k0] = *(uint4*)&hiP[0];
            *(uint4*)&hL[m * 264 + k0] = *(uint4*)&loP[0];
        }
    }
    __syncthreads();

    // ---- phase B: h1 = relu(h0 @ W1 + b1); 4 M-tiles, 4 N-tiles ----
    f32x4 acc[4][4];
    #pragma unroll
    for (int mt = 0; mt < 4; ++mt)
        #pragma unroll
        for (int nt = 0; nt < 4; ++nt) acc[mt][nt] = (f32x4){0.f, 0.f, 0.f, 0.f};

    {
        const u16* pB = wsW1 + (nq * 64 + ln) * 32 + q * 8;
        bf16x8 CBh[4], CBl[4];                     // current B-frags
        #pragma unroll
        for (int nt = 0; nt < 4; ++nt) {
            CBh[nt] = *(const bf16x8*)(pB + nt * 512);
            CBl[nt] = *(const bf16x8*)(pB + 8192 + nt * 512);
        }
        #pragma unroll
        for (int s = 0; s < 8; ++s) {
            bf16x8 AH[4], AL[4];
            #pragma unroll
            for (int mt = 0; mt < 4; ++mt) {
                const int ao = (mt * 16 + ln) * 264 + s * 32 + q * 8;
                AH[mt] = *(const bf16x8*)&hH[ao];
                AL[mt] = *(const bf16x8*)&hL[ao];
            }
            bf16x8 NBh[4], NBl[4];                 // prefetch s+1 B-frags
            if (s < 7) {
                const u16* pn = pB + (s + 1) * 16384;
                #pragma unroll
                for (int nt = 0; nt < 4; ++nt) {
                    NBh[nt] = *(const bf16x8*)(pn + nt * 512);
                    NBl[nt] = *(const bf16x8*)(pn + 8192 + nt * 512);
                }
            }
            #pragma unroll
            for (int nt = 0; nt < 4; ++nt) {
                #pragma unroll
                for (int mt = 0; mt < 4; ++mt) {
                    f32x4 a = acc[mt][nt];
                    a = __builtin_amdgcn_mfma_f32_16x16x32_bf16(AH[mt], CBh[nt], a, 0, 0, 0);
                    a = __builtin_amdgcn_mfma_f32_16x16x32_bf16(AH[mt], CBl[nt], a, 0, 0, 0);
                    a = __builtin_amdgcn_mfma_f32_16x16x32_bf16(AL[mt], CBh[nt], a, 0, 0, 0);
                    acc[mt][nt] = a;
                }
            }
            if (s < 7) {
                #pragma unroll
                for (int nt = 0; nt < 4; ++nt) { CBh[nt] = NBh[nt]; CBl[nt] = NBl[nt]; }
            }
        }
    }
    __syncthreads();                 // all h0 reads done before h1 overlay

    {   // h1 epilogue: relu(+b1), split -> hH/hL (u16 scatter writes)
        #pragma unroll
        for (int nt = 0; nt < 4; ++nt) {
            const int n = nq * 64 + nt * 16 + ln;
            const float b1 = B1[n];
            #pragma unroll
            for (int mt = 0; mt < 4; ++mt) {
                #pragma unroll
                for (int r = 0; r < 4; ++r) {
                    float h = fmaxf(acc[mt][nt][r] + b1, 0.f);
                    u32 rh = rneu(h);
                    u32 rl = rneu(h - maskf(rh));
                    const int mr = mt * 16 + q * 4 + r;
                    hH[mr * 264 + n] = (u16)(rh >> 16);
                    hL[mr * 264 + n] = (u16)(rl >> 16);
                }
            }
        }
    }
    __syncthreads();

    // ---- phase C: emb = h1 @ W2 + b2 (ALL waves; M-tile = wv) ----
    {
        f32x4 ac = (f32x4){0.f, 0.f, 0.f, 0.f};
        const int abase = (wv * 16 + ln) * 264 + q * 8;
        const u16* pWh = wsW2 + ln * 264 + q * 8;
        const u16* pWl = pWh + 4224;
        bf16x8 CWh = *(const bf16x8*)(pWh);
        bf16x8 CWl = *(const bf16x8*)(pWl);
        #pragma unroll
        for (int s = 0; s < 8; ++s) {
            bf16x8 NWh, NWl;                       // prefetch s+1 W2 frags
            if (s < 7) {
                NWh = *(const bf16x8*)(pWh + (s + 1) * 32);
                NWl = *(const bf16x8*)(pWl + (s + 1) * 32);
            }
            bf16x8 Ah2 = *(const bf16x8*)&hH[abase + s * 32];
            bf16x8 Al2 = *(const bf16x8*)&hL[abase + s * 32];
            ac = __builtin_amdgcn_mfma_f32_16x16x32_bf16(Ah2, CWh, ac, 0, 0, 0);
            ac = __builtin_amdgcn_mfma_f32_16x16x32_bf16(Ah2, CWl, ac, 0, 0, 0);
            ac = __builtin_amdgcn_mfma_f32_16x16x32_bf16(Al2, CWh, ac, 0, 0, 0);
            if (s < 7) { CWh = NWh; CWl = NWl; }
        }
        const float b2 = B2[ln];
        #pragma unroll
        for (int r = 0; r < 4; ++r) {
            float e = ac[r] + b2;
            u32 rh = rneu(e);
            u32 rl = rneu(e - maskf(rh));
            const int row = wv * 16 + q * 4 + r;
            embsH[row * 24 + ln] = (u16)(rh >> 16);
            embsL[row * 24 + ln] = (u16)(rl >> 16);
        }
    }
    __syncthreads();                 // emb planes ready

    // ---- phase D: wave = code quarter (8 tiles); 4 token-sets ----
    {
        const u16* ebase = (q < 2) ? embsH : embsL;
        bf16x8 Ae[4];                // K-packed: q<2 -> e_hi, q>=2 -> e_lo
        #pragma unroll
        for (int ms = 0; ms < 4; ++ms)
            Ae[ms] = *(const bf16x8*)&ebase[(ms * 16 + ln) * 24 + (q & 1) * 8];

        float cn8[8];
        #pragma unroll
        for (int tb = 0; tb < 8; ++tb) cn8[tb] = n32[(wv * 8 + tb) * 16 + ln];

        // hoist ALL 8 codebook tile frags into registers (one load burst)
        const u16* pC = wsCB + (wv * 8) * 1024 + l * 8;
        bf16x8 TBh[8], TBl[8];
        #pragma unroll
        for (int tb = 0; tb < 8; ++tb) {
            TBh[tb] = *(const bf16x8*)(pC + tb * 1024);
            TBl[tb] = *(const bf16x8*)(pC + tb * 1024 + 512);
        }

        float d1[4][4], d2[4][4]; int i1[4][4];
        #pragma unroll
        for (int ms = 0; ms < 4; ++ms)
            #pragma unroll
            for (int r = 0; r < 4; ++r) {
                d1[ms][r] = d2[ms][r] = 3.4e38f;
                i1[ms][r] = 0x7fffffff;
            }

        #pragma unroll
        for (int tb = 0; tb < 8; ++tb) {
            const int ci = (wv * 8 + tb) * 16 + ln;
            #pragma unroll
            for (int ms = 0; ms < 4; ++ms) {
                f32x4 a = (f32x4){0.f, 0.f, 0.f, 0.f};
                a = __builtin_amdgcn_mfma_f32_16x16x32_bf16(Ae[ms], TBh[tb], a, 0, 0, 0);
                a = __builtin_amdgcn_mfma_f32_16x16x32_bf16(Ae[ms], TBl[tb], a, 0, 0, 0);
                #pragma unroll
                for (int r = 0; r < 4; ++r) {
                    float d = fmaf(-2.f, a[r], cn8[tb]);
                    bool lt = d < d1[ms][r];
                    d2[ms][r] = fminf(d2[ms][r], fmaxf(d1[ms][r], d));
                    d1[ms][r] = fminf(d1[ms][r], d);
                    i1[ms][r] = lt ? ci : i1[ms][r];
                }
            }
        }
        // reduce over the 16 lanes of the quad. NOTE: no index tie-break —
        // a tie at the minimum forces d2==d1 (<EPS) -> fp64 fixup resolves.
        #pragma unroll
        for (int off = 8; off >= 1; off >>= 1) {
            #pragma unroll
            for (int ms = 0; ms < 4; ++ms)
                #pragma unroll
                for (int r = 0; r < 4; ++r) {
                    float od1 = __shfl_down(d1[ms][r], off, 16);
                    int   oi1 = __shfl_down(i1[ms][r], off, 16);
                    float od2 = __shfl_down(d2[ms][r], off, 16);
                    bool ob = od1 < d1[ms][r];
                    float hi2 = fmaxf(d1[ms][r], od1);
                    d1[ms][r] = fminf(d1[ms][r], od1);
                    i1[ms][r] = ob ? oi1 : i1[ms][r];
                    d2[ms][r] = fminf(fminf(d2[ms][r], od2), hi2);
                }
        }
        if (ln == 0) {
            #pragma unroll
            for (int ms = 0; ms < 4; ++ms)
                #pragma unroll
                for (int r = 0; r < 4; ++r) {
                    const int m = ms * 16 + q * 4 + r;
                    redD[wv][m][0] = d1[ms][r]; redD[wv][m][1] = d2[ms][r];
                    redI[wv][m] = i1[ms][r];
                }
        }
    }
    __syncthreads();

    if (tid < 64) {                  // merge 4 quarters, flag, write idx
        const int m = tid;
        float d1 = redD[0][m][0], d2 = redD[0][m][1];
        int   i1 = redI[0][m];
        #pragma unroll
        for (int h = 1; h < 4; ++h) {
            float a1 = redD[h][m][0], a2 = redD[h][m][1];
            int   ai = redI[h][m];
            bool ob = a1 < d1;       // tie -> flagged -> fixup resolves
            float hi2 = fmaxf(d1, a1);
            d1 = fminf(d1, a1);
            i1 = ob ? ai : i1;
            d2 = fminf(fminf(d2, a2), hi2);
        }
        const int T = blk * 64 + m;
        idxbuf[T] = i1;
        if (d2 - d1 < EPS) {
            int pos = atomicAdd(fcnt, 1);
            flist[pos] = T;
        }
    }
}

// ---------------------------------------------------------------------------
// Kernel 2: fp64 exact re-solve for flagged tokens (from ORIGINAL fp32 data).
// ---------------------------------------------------------------------------
__global__ void __launch_bounds__(256) fixup_kernel(
    const float* __restrict__ obs,
    const float* __restrict__ W0, const float* __restrict__ B0,
    const float* __restrict__ W1, const float* __restrict__ B1,
    const float* __restrict__ W2, const float* __restrict__ B2,
    const float* __restrict__ cb, const double* __restrict__ n64,
    const int* __restrict__ fcnt, const int* __restrict__ flist,
    int* __restrict__ idxbuf)
{
    __shared__ double h0s[HD];
    __shared__ double h1s[HD];
    __shared__ double ep[16][17];
    __shared__ double es[CD];
    __shared__ double dmin[256];
    __shared__ int    imin[256];

    int n = *fcnt;
    if (n > BATCH * OBS) n = BATCH * OBS;
    const int j = threadIdx.x;

    for (int f = blockIdx.x; f < n; f += gridDim.x) {
        const int T = flist[f];
        const int b = T >> 5, t = T & 31;
        const double x = (double)obs[b * OBS + t];
        {
            double a = fma(x, (double)W0[j], (double)W0[(1 + t) * HD + j])
                     + (double)B0[j];
            h0s[j] = a > 0.0 ? a : 0.0;
        }
        __syncthreads();
        {
            double s = 0.0;
            for (int k = 0; k < HD; ++k)
                s = fma(h0s[k], (double)W1[k * HD + j], s);
            s += (double)B1[j];
            h1s[j] = s > 0.0 ? s : 0.0;
        }
        __syncthreads();
        {
            const int d = j & 15, part = j >> 4;
            double s = 0.0;
            for (int k = part * 16; k < part * 16 + 16; ++k)
                s = fma(h1s[k], (double)W2[k * CD + d], s);
            ep[part][d] = s;
        }
        __syncthreads();
        if (j < CD) {
            double s = 0.0;
            for (int p = 0; p < 16; ++p) s += ep[p][j];
            es[j] = s + (double)B2[j];
        }
        __syncthreads();
        {
            double best = 1e300; int bi = 0x7fffffff;
            for (int c = j; c < NC; c += 256) {
                double dot = 0.0;
                #pragma unroll
                for (int qq = 0; qq < CD; ++qq)
                    dot = fma(es[qq], (double)cb[c * CD + qq], dot);
                double D = n64[c] - 2.0 * dot;
                if (D < best || (D == best && c < bi)) { best = D; bi = c; }
            }
            dmin[j] = best; imin[j] = bi;
        }
        __syncthreads();
        if (j == 0) {
            double best = dmin[0]; int bi = imin[0];
            for (int k = 1; k < 256; ++k)
                if (dmin[k] < best || (dmin[k] == best && imin[k] < bi)) {
                    best = dmin[k]; bi = imin[k];
                }
            idxbuf[T] = bi;
        }
        __syncthreads();
    }
}

// ---------------------------------------------------------------------------
// Kernel 3: decoder MLP 512 -> 256 -> 256 -> 32, 16 batch rows per block
// (round-4 measured config — do not restructure: absmax 0.0 depends on the
// exact fp32 accumulation order).
// ---------------------------------------------------------------------------
__global__ void __launch_bounds__(256) decoder_kernel(
    const int* __restrict__ idx, const float* __restrict__ cbk,
    const float* __restrict__ W0, const float* __restrict__ B0,
    const float* __restrict__ W1, const float* __restrict__ B1,
    const float* __restrict__ W2, const float* __restrict__ B2,
    float* __restrict__ out)
{
    __shared__ float qb[16][512];
    __shared__ float hb[16][256];
    const int tid = threadIdx.x;
    const int row0 = blockIdx.x * 16;

    {
        const int base = row0 * OBS;
        #pragma unroll
        for (int m = 0; m < 2; ++m) {
            int g = tid * 2 + m;
            int ciq = idx[base + g];
            const float4* src = (const float4*)(cbk + ciq * CD);
            float4* dst = (float4*)&qb[g >> 5][(g & 31) * CD];
            dst[0] = src[0]; dst[1] = src[1]; dst[2] = src[2]; dst[3] = src[3];
        }
    }
    __syncthreads();

    const int jg = tid & 63, tg = tid >> 6;
    const int j0 = jg * 4, r0 = tg * 4;

    {
        float acA[4][4], acB[4][4];
        #pragma unroll
        for (int tt = 0; tt < 4; ++tt)
            #pragma unroll
            for (int u = 0; u < 4; ++u) { acA[tt][u] = 0.f; acB[tt][u] = 0.f; }
        for (int k = 0; k < 512; k += 4) {
            float hr[4][4];
            #pragma unroll
            for (int tt = 0; tt < 4; ++tt) {
                float4 hv = *(const float4*)&qb[r0 + tt][k];
                hr[tt][0] = hv.x; hr[tt][1] = hv.y; hr[tt][2] = hv.z; hr[tt][3] = hv.w;
            }
            #pragma unroll
            for (int p = 0; p < 4; ++p) {
                float4 w = *(const float4*)(W0 + (k + p) * 256 + j0);
                if (p < 2) {
                    #pragma unroll
                    for (int tt = 0; tt < 4; ++tt) {
                        acA[tt][0] = fmaf(hr[tt][p], w.x, acA[tt][0]);
                        acA[tt][1] = fmaf(hr[tt][p], w.y, acA[tt][1]);
                        acA[tt][2] = fmaf(hr[tt][p], w.z, acA[tt][2]);
                        acA[tt][3] = fmaf(hr[tt][p], w.w, acA[tt][3]);
                    }
                } else {
                    #pragma unroll
                    for (int tt = 0; tt < 4; ++tt) {
                        acB[tt][0] = fmaf(hr[tt][p], w.x, acB[tt][0]);
                        acB[tt][1] = fmaf(hr[tt][p], w.y, acB[tt][1]);
                        acB[tt][2] = fmaf(hr[tt][p], w.z, acB[tt][2]);
                        acB[tt][3] = fmaf(hr[tt][p], w.w, acB[tt][3]);
                    }
                }
            }
        }
        #pragma unroll
        for (int tt = 0; tt < 4; ++tt)
            #pragma unroll
            for (int u = 0; u < 4; ++u)
                hb[r0 + tt][j0 + u] = fmaxf((acA[tt][u] + acB[tt][u]) + B0[j0 + u], 0.f);
    }
    __syncthreads();

    float* h2 = &qb[0][0];
    {
        float acA[4][4], acB[4][4];
        #pragma unroll
        for (int tt = 0; tt < 4; ++tt)
            #pragma unroll
            for (int u = 0; u < 4; ++u) { acA[tt][u] = 0.f; acB[tt][u] = 0.f; }
        for (int k = 0; k < 256; k += 4) {
            float hr[4][4];
            #pragma unroll
            for (int tt = 0; tt < 4; ++tt) {
                float4 hv = *(const float4*)&hb[r0 + tt][k];
                hr[tt][0] = hv.x; hr[tt][1] = hv.y; hr[tt][2] = hv.z; hr[tt][3] = hv.w;
            }
            #pragma unroll
            for (int p = 0; p < 4; ++p) {
                float4 w = *(const float4*)(W1 + (k + p) * 256 + j0);
                if (p < 2) {
                    #pragma unroll
                    for (int tt = 0; tt < 4; ++tt) {
                        acA[tt][0] = fmaf(hr[tt][p], w.x, acA[tt][0]);
                        acA[tt][1] = fmaf(hr[tt][p], w.y, acA[tt][1]);
                        acA[tt][2] = fmaf(hr[tt][p], w.z, acA[tt][2]);
                        acA[tt][3] = fmaf(hr[tt][p], w.w, acA[tt][3]);
                    }
                } else {
                    #pragma unroll
                    for (int tt = 0; tt < 4; ++tt) {
                        acB[tt][0] = fmaf(hr[tt][p], w.x, acB[tt][0]);
                        acB[tt][1] = fmaf(hr[tt][p], w.y, acB[tt][1]);
                        acB[tt][2] = fmaf(hr[tt][p], w.z, acB[tt][2]);
                        acB[tt][3] = fmaf(hr[tt][p], w.w, acB[tt][3]);
                    }
                }
            }
        }
        __syncthreads();
        #pragma unroll
        for (int tt = 0; tt < 4; ++tt)
            #pragma unroll
            for (int u = 0; u < 4; ++u)
                h2[(r0 + tt) * 256 + j0 + u] =
                    fmaxf((acA[tt][u] + acB[tt][u]) + B1[j0 + u], 0.f);
    }
    __syncthreads();

    {
        const int c  = tid & 31;
        const int rg = tid >> 5;
        for (int rr = rg; rr < 16; rr += 8) {
            float a0 = 0.f, a1 = 0.f, a2 = 0.f, a3 = 0.f;
            #pragma unroll 4
            for (int k = 0; k < 256; k += 4) {
                float4 hv = *(const float4*)&h2[rr * 256 + k];
                a0 = fmaf(hv.x, W2[(k + 0) * 32 + c], a0);
                a1 = fmaf(hv.y, W2[(k + 1) * 32 + c], a1);
                a2 = fmaf(hv.z, W2[(k + 2) * 32 + c], a2);
                a3 = fmaf(hv.w, W2[(k + 3) * 32 + c], a3);
            }
            out[(row0 + rr) * 32 + c] = ((a0 + a1) + (a2 + a3)) + B2[c];
        }
    }
}

// ---------------------------------------------------------------------------
extern "C" void kernel_launch(void* const* d_in, const int* in_sizes, int n_in,
                              void* d_out, int out_size, void* d_ws, size_t ws_size,
                              hipStream_t stream) {
    (void)in_sizes; (void)n_in; (void)out_size; (void)ws_size;
    const float* obs = (const float*)d_in[0];
    const float* eW0 = (const float*)d_in[1];
    const float* eb0 = (const float*)d_in[2];
    const float* eW1 = (const float*)d_in[3];
    const float* eb1 = (const float*)d_in[4];
    const float* eW2 = (const float*)d_in[5];
    const float* eb2 = (const float*)d_in[6];
    const float* dW0 = (const float*)d_in[7];
    const float* db0 = (const float*)d_in[8];
    const float* dW1 = (const float*)d_in[9];
    const float* db1 = (const float*)d_in[10];
    const float* dW2 = (const float*)d_in[11];
    const float* db2 = (const float*)d_in[12];
    const float* cb  = (const float*)d_in[13];

    char*   ws    = (char*)d_ws;
    float*  n32   = (float*)ws;                          // 2 KB
    double* n64   = (double*)(ws + 4096);                // 4 KB
    int*    fcnt  = (int*)(ws + 8192);                   // 4 B
    int*    flist = (int*)(ws + 8448);                   // 1 MB
    int*    idxb  = (int*)(ws + 8448 + 1048576);         // 1 MB (ends 2105600)
    float*  w0m   = (float*)(ws + 3145728);              // 32 KB (gap before wsW1)
    u16*    wsW1  = (u16*)(ws + 4194304);                // 256 KB
    u16*    wsW2  = (u16*)(ws + 4194304 + 262144);       // 16.5 KB (pad 32 KB)
    u16*    wsCB  = (u16*)(ws + 4194304 + 262144 + 32768); // 64 KB

    prep_kernel<<<260, 256, 0, stream>>>(cb, eW1, eW2, eW0, eb0, n32, n64, fcnt,
                                         wsW1, wsW2, wsCB, w0m);
    encoder_kernel<<<BATCH / 2, 256, 0, stream>>>(obs, eW0, w0m, eb1, eb2,
                                                  wsW1, wsW2, wsCB, n32,
                                                  idxb, fcnt, flist);
    fixup_kernel<<<256, 256, 0, stream>>>(obs, eW0, eb0, eW1, eb1, eW2, eb2,
                                          cb, n64, fcnt, flist, idxb);
    decoder_kernel<<<BATCH / 16, 256, 0, stream>>>(idxb, cb, dW0, db0, dW1, db1,
                                                   dW2, db2, (float*)d_out);
}

// Round 13
// 345.106 us; speedup vs baseline: 1.1971x; 1.1971x over previous
//
#include <hip/hip_runtime.h>

#define OBS   32
#define NC    512
#define CD    16
#define HD    256
#define BATCH 8192
#define EPS   4e-3f

typedef unsigned short u16;
typedef unsigned int   u32;
typedef __attribute__((ext_vector_type(8))) short bf16x8;   // 8 bf16 = 4 VGPR
typedef __attribute__((ext_vector_type(4))) float f32x4;

__device__ __forceinline__ short f2bf(float x) {            // fp32 -> bf16 RNE
    union { float f; u32 u; } v; v.f = x;
    u32 r = (v.u + 0x7fffu + ((v.u >> 16) & 1u)) >> 16;
    return (short)r;
}
__device__ __forceinline__ float bf2f(short s) {
    union { u32 u; float f; } v; v.u = ((u32)(u16)s) << 16; return v.f;
}

// ---------------------------------------------------------------------------
// Kernel 0 (prep): norms + fcnt; W1 split hi/lo in B-frag chunk order;
// W2t split (stride 264); codebook B-frags; W0m = W0[1+m] + b0 fold.
// ---------------------------------------------------------------------------
__global__ void prep_kernel(const float* __restrict__ cb,
                            const float* __restrict__ W1,
                            const float* __restrict__ W2,
                            const float* __restrict__ W0,
                            const float* __restrict__ B0,
                            float* __restrict__ n32, double* __restrict__ n64,
                            int* __restrict__ fcnt,
                            u16* __restrict__ wsW1, u16* __restrict__ wsW2,
                            u16* __restrict__ wsCB, float* __restrict__ w0m) {
    const int b = blockIdx.x, t = threadIdx.x;
    if (b == 0) {
        if (t == 0) *fcnt = 0;
        #pragma unroll
        for (int h = 0; h < 2; ++h) {
            int c = t + h * 256;
            const float* r = cb + c * CD;
            float s32 = 0.f; double s64 = 0.0;
            #pragma unroll
            for (int j = 0; j < CD; ++j) {
                float v = r[j];
                s32 = fmaf(v, v, s32);
                s64 = fma((double)v, (double)v, s64);
            }
            n32[c] = s32; n64[c] = s64;
        }
    } else if (b <= 256) {
        int e = (b - 1) * 256 + t;          // e = k*256 + n
        int k = e >> 8, n = e & 255;
        float w = W1[k * 256 + n];
        short hi = f2bf(w);
        short lo = f2bf(w - bf2f(hi));
        int s = k >> 5, koff = k & 31;
        wsW1[s * 16384 + n * 32 + koff]        = (u16)hi;
        wsW1[s * 16384 + 8192 + n * 32 + koff] = (u16)lo;
    } else if (b == 257) {                   // W2 (4096 elems)
        #pragma unroll
        for (int i = 0; i < 16; ++i) {
            int e = t * 16 + i;              // e = k*16 + n
            int k = e >> 4, n = e & 15;
            float w = W2[k * CD + n];
            short hi = f2bf(w);
            short lo = f2bf(w - bf2f(hi));
            wsW2[n * 264 + k]        = (u16)hi;
            wsW2[4224 + n * 264 + k] = (u16)lo;
        }
    } else if (b == 258) {                   // codebook B-frags
        #pragma unroll
        for (int i = 0; i < 8; ++i) {
            int sl = t * 8 + i;              // (tile, lane) slot, 2048 total
            int tile = sl >> 6, l = sl & 63;
            int n  = tile * 16 + (l & 15);
            int kb = ((l >> 4) & 1) * 8;
            u16* dh = wsCB + tile * 1024 + l * 8;
            u16* dl = dh + 512;
            #pragma unroll
            for (int j = 0; j < 8; ++j) {
                float w = cb[n * CD + kb + j];
                short hi = f2bf(w);
                dh[j] = (u16)hi;
                dl[j] = (u16)f2bf(w - bf2f(hi));
            }
        }
    } else {                                 // b == 259: W0m = W0[1+m] + b0
        #pragma unroll
        for (int m = 0; m < OBS; ++m)
            w0m[m * HD + t] = W0[(1 + m) * HD + t] + B0[t];
    }
}

// ---------------------------------------------------------------------------
// Kernel 1: MFMA encoder — TWO batch rows (64 tokens) per block, 256 thr.
// Register prefetch of ALL global operands: phase-B W1 B-frags (dbuf s+1),
// phase-C W2 frags (dbuf s+1), phase-D codebook frags (all 8 tiles hoisted).
// Measured-best config (round 11: 201 us encoder, VGPR 112, 2 blk/CU).
// NOTE: do NOT raise VGPR past 128 — occupancy cliff (round-12 regression).
// ---------------------------------------------------------------------------
__global__ void __launch_bounds__(256) encoder_kernel(
    const float* __restrict__ obs,
    const float* __restrict__ W0, const float* __restrict__ w0m,
    const float* __restrict__ B1, const float* __restrict__ B2,
    const u16* __restrict__ wsW1, const u16* __restrict__ wsW2,
    const u16* __restrict__ wsCB, const float* __restrict__ n32,
    int* __restrict__ idxbuf, int* __restrict__ fcnt, int* __restrict__ flist)
{
    __shared__ __align__(16) u16  hH[64 * 264];    // 33792 B  hi plane
    __shared__ __align__(16) u16  hL[64 * 264];    // 33792 B  lo plane
    __shared__ __align__(16) u16  embsH[64 * 24];  //  3072 B  emb hi plane
    __shared__ __align__(16) u16  embsL[64 * 24];  //  3072 B  emb lo plane
    __shared__ float redD[4][64][2];               //  2048 B
    __shared__ int   redI[4][64];                  //  1024 B  (76800 B -> 2 blk/CU)

    const int tid = threadIdx.x;
    const int blk = blockIdx.x;
    const int l   = tid & 63;
    const int wv  = tid >> 6;
    const int q   = l >> 4;          // quad 0..3
    const int ln  = l & 15;
    const int nq  = wv;              // N-quarter (cols nq*64 .. +63)

    // ---- phase A (ALL waves): token m = tid>>2 (0..63), 4 lanes/token ----
    {
        const int m = tid >> 2;          // 0..63  (row m>>5, tok m&31)
        const int p = tid & 3;           // k-chunk lane
        const float x = obs[blk * 64 + m];
        const float* W0m = w0m + (m & 31) * HD;
        #pragma unroll
        for (int s = 0; s < 8; ++s) {
            const int k0 = s * 32 + p * 8;
            float w0v[8], wmv[8];
            *(float4*)&w0v[0] = *(const float4*)(W0 + k0);
            *(float4*)&w0v[4] = *(const float4*)(W0 + k0 + 4);
            *(float4*)&wmv[0] = *(const float4*)(W0m + k0);
            *(float4*)&wmv[4] = *(const float4*)(W0m + k0 + 4);
            u32 hiP[4], loP[4];
            #pragma unroll
            for (int jp = 0; jp < 4; ++jp) {
                float ha = fmaxf(fmaf(x, w0v[2 * jp],     wmv[2 * jp]),     0.f);
                float hb = fmaxf(fmaf(x, w0v[2 * jp + 1], wmv[2 * jp + 1]), 0.f);
                short h0 = f2bf(ha), h1 = f2bf(hb);
                short l0 = f2bf(ha - bf2f(h0)), l1 = f2bf(hb - bf2f(h1));
                hiP[jp] = ((u32)(u16)h1 << 16) | (u32)(u16)h0;
                loP[jp] = ((u32)(u16)l1 << 16) | (u32)(u16)l0;
            }
            *(uint4*)&hH[m * 264 + k0] = *(uint4*)&hiP[0];
            *(uint4*)&hL[m * 264 + k0] = *(uint4*)&loP[0];
        }
    }
    __syncthreads();

    // ---- phase B: h1 = relu(h0 @ W1 + b1); 4 M-tiles, 4 N-tiles ----
    f32x4 acc[4][4];
    #pragma unroll
    for (int mt = 0; mt < 4; ++mt)
        #pragma unroll
        for (int nt = 0; nt < 4; ++nt) acc[mt][nt] = (f32x4){0.f, 0.f, 0.f, 0.f};

    {
        const u16* pB = wsW1 + (nq * 64 + ln) * 32 + q * 8;
        bf16x8 CBh[4], CBl[4];                     // current B-frags
        #pragma unroll
        for (int nt = 0; nt < 4; ++nt) {
            CBh[nt] = *(const bf16x8*)(pB + nt * 512);
            CBl[nt] = *(const bf16x8*)(pB + 8192 + nt * 512);
        }
        #pragma unroll
        for (int s = 0; s < 8; ++s) {
            bf16x8 AH[4], AL[4];
            #pragma unroll
            for (int mt = 0; mt < 4; ++mt) {
                const int ao = (mt * 16 + ln) * 264 + s * 32 + q * 8;
                AH[mt] = *(const bf16x8*)&hH[ao];
                AL[mt] = *(const bf16x8*)&hL[ao];
            }
            bf16x8 NBh[4], NBl[4];                 // prefetch s+1 B-frags
            if (s < 7) {
                const u16* pn = pB + (s + 1) * 16384;
                #pragma unroll
                for (int nt = 0; nt < 4; ++nt) {
                    NBh[nt] = *(const bf16x8*)(pn + nt * 512);
                    NBl[nt] = *(const bf16x8*)(pn + 8192 + nt * 512);
                }
            }
            #pragma unroll
            for (int nt = 0; nt < 4; ++nt) {
                #pragma unroll
                for (int mt = 0; mt < 4; ++mt) {
                    f32x4 a = acc[mt][nt];
                    a = __builtin_amdgcn_mfma_f32_16x16x32_bf16(AH[mt], CBh[nt], a, 0, 0, 0);
                    a = __builtin_amdgcn_mfma_f32_16x16x32_bf16(AH[mt], CBl[nt], a, 0, 0, 0);
                    a = __builtin_amdgcn_mfma_f32_16x16x32_bf16(AL[mt], CBh[nt], a, 0, 0, 0);
                    acc[mt][nt] = a;
                }
            }
            if (s < 7) {
                #pragma unroll
                for (int nt = 0; nt < 4; ++nt) { CBh[nt] = NBh[nt]; CBl[nt] = NBl[nt]; }
            }
        }
    }
    __syncthreads();                 // all h0 reads done before h1 overlay

    {   // h1 epilogue: relu(+b1), split -> hH/hL (u16 scatter writes)
        #pragma unroll
        for (int nt = 0; nt < 4; ++nt) {
            const int n = nq * 64 + nt * 16 + ln;
            const float b1 = B1[n];
            #pragma unroll
            for (int mt = 0; mt < 4; ++mt) {
                #pragma unroll
                for (int r = 0; r < 4; ++r) {
                    float h = fmaxf(acc[mt][nt][r] + b1, 0.f);
                    short hi = f2bf(h);
                    short lo = f2bf(h - bf2f(hi));
                    const int mr = mt * 16 + q * 4 + r;
                    hH[mr * 264 + n] = (u16)hi;
                    hL[mr * 264 + n] = (u16)lo;
                }
            }
        }
    }
    __syncthreads();

    // ---- phase C: emb = h1 @ W2 + b2 (ALL waves; M-tile = wv) ----
    {
        f32x4 ac = (f32x4){0.f, 0.f, 0.f, 0.f};
        const int abase = (wv * 16 + ln) * 264 + q * 8;
        const u16* pWh = wsW2 + ln * 264 + q * 8;
        const u16* pWl = pWh + 4224;
        bf16x8 CWh = *(const bf16x8*)(pWh);
        bf16x8 CWl = *(const bf16x8*)(pWl);
        #pragma unroll
        for (int s = 0; s < 8; ++s) {
            bf16x8 NWh, NWl;                       // prefetch s+1 W2 frags
            if (s < 7) {
                NWh = *(const bf16x8*)(pWh + (s + 1) * 32);
                NWl = *(const bf16x8*)(pWl + (s + 1) * 32);
            }
            bf16x8 Ah2 = *(const bf16x8*)&hH[abase + s * 32];
            bf16x8 Al2 = *(const bf16x8*)&hL[abase + s * 32];
            ac = __builtin_amdgcn_mfma_f32_16x16x32_bf16(Ah2, CWh, ac, 0, 0, 0);
            ac = __builtin_amdgcn_mfma_f32_16x16x32_bf16(Ah2, CWl, ac, 0, 0, 0);
            ac = __builtin_amdgcn_mfma_f32_16x16x32_bf16(Al2, CWh, ac, 0, 0, 0);
            if (s < 7) { CWh = NWh; CWl = NWl; }
        }
        const float b2 = B2[ln];
        #pragma unroll
        for (int r = 0; r < 4; ++r) {
            float e = ac[r] + b2;
            short hi = f2bf(e);
            short lo = f2bf(e - bf2f(hi));
            const int row = wv * 16 + q * 4 + r;
            embsH[row * 24 + ln] = (u16)hi;
            embsL[row * 24 + ln] = (u16)lo;
        }
    }
    __syncthreads();                 // emb planes ready

    // ---- phase D: wave = code quarter (8 tiles); 4 token-sets ----
    {
        const u16* ebase = (q < 2) ? embsH : embsL;
        bf16x8 Ae[4];                // K-packed: q<2 -> e_hi, q>=2 -> e_lo
        #pragma unroll
        for (int ms = 0; ms < 4; ++ms)
            Ae[ms] = *(const bf16x8*)&ebase[(ms * 16 + ln) * 24 + (q & 1) * 8];

        float cn8[8];
        #pragma unroll
        for (int tb = 0; tb < 8; ++tb) cn8[tb] = n32[(wv * 8 + tb) * 16 + ln];

        // hoist ALL 8 codebook tile frags into registers (one load burst)
        const u16* pC = wsCB + (wv * 8) * 1024 + l * 8;
        bf16x8 TBh[8], TBl[8];
        #pragma unroll
        for (int tb = 0; tb < 8; ++tb) {
            TBh[tb] = *(const bf16x8*)(pC + tb * 1024);
            TBl[tb] = *(const bf16x8*)(pC + tb * 1024 + 512);
        }

        float d1[4][4], d2[4][4]; int i1[4][4];
        #pragma unroll
        for (int ms = 0; ms < 4; ++ms)
            #pragma unroll
            for (int r = 0; r < 4; ++r) {
                d1[ms][r] = d2[ms][r] = 3.4e38f;
                i1[ms][r] = 0x7fffffff;
            }

        #pragma unroll
        for (int tb = 0; tb < 8; ++tb) {
            const int ci = (wv * 8 + tb) * 16 + ln;
            #pragma unroll
            for (int ms = 0; ms < 4; ++ms) {
                f32x4 a = (f32x4){0.f, 0.f, 0.f, 0.f};
                a = __builtin_amdgcn_mfma_f32_16x16x32_bf16(Ae[ms], TBh[tb], a, 0, 0, 0);
                a = __builtin_amdgcn_mfma_f32_16x16x32_bf16(Ae[ms], TBl[tb], a, 0, 0, 0);
                #pragma unroll
                for (int r = 0; r < 4; ++r) {
                    float d = fmaf(-2.f, a[r], cn8[tb]);
                    bool lt = d < d1[ms][r];
                    d2[ms][r] = fminf(d2[ms][r], fmaxf(d1[ms][r], d));
                    d1[ms][r] = fminf(d1[ms][r], d);
                    i1[ms][r] = lt ? ci : i1[ms][r];
                }
            }
        }
        // reduce over the 16 lanes of the quad (tie -> low index)
        #pragma unroll
        for (int off = 8; off >= 1; off >>= 1) {
            #pragma unroll
            for (int ms = 0; ms < 4; ++ms)
                #pragma unroll
                for (int r = 0; r < 4; ++r) {
                    float od1 = __shfl_down(d1[ms][r], off, 16);
                    int   oi1 = __shfl_down(i1[ms][r], off, 16);
                    float od2 = __shfl_down(d2[ms][r], off, 16);
                    bool ob = (od1 < d1[ms][r]) ||
                              (od1 == d1[ms][r] && oi1 < i1[ms][r]);
                    float hi2 = fmaxf(d1[ms][r], od1);
                    d1[ms][r] = fminf(d1[ms][r], od1);
                    i1[ms][r] = ob ? oi1 : i1[ms][r];
                    d2[ms][r] = fminf(fminf(d2[ms][r], od2), hi2);
                }
        }
        if (ln == 0) {
            #pragma unroll
            for (int ms = 0; ms < 4; ++ms)
                #pragma unroll
                for (int r = 0; r < 4; ++r) {
                    const int m = ms * 16 + q * 4 + r;
                    redD[wv][m][0] = d1[ms][r]; redD[wv][m][1] = d2[ms][r];
                    redI[wv][m] = i1[ms][r];
                }
        }
    }
    __syncthreads();

    if (tid < 64) {                  // merge 4 quarters, flag, write idx
        const int m = tid;
        float d1 = redD[0][m][0], d2 = redD[0][m][1];
        int   i1 = redI[0][m];
        #pragma unroll
        for (int h = 1; h < 4; ++h) {
            float a1 = redD[h][m][0], a2 = redD[h][m][1];
            int   ai = redI[h][m];
            bool ob = (a1 < d1) || (a1 == d1 && ai < i1);
            float hi2 = fmaxf(d1, a1);
            d1 = fminf(d1, a1);
            i1 = ob ? ai : i1;
            d2 = fminf(fminf(d2, a2), hi2);
        }
        const int T = blk * 64 + m;
        idxbuf[T] = i1;
        if (d2 - d1 < EPS) {
            int pos = atomicAdd(fcnt, 1);
            flist[pos] = T;
        }
    }
}

// ---------------------------------------------------------------------------
// Kernel 2: fp64 exact re-solve for flagged tokens (from ORIGINAL fp32 data).
// ---------------------------------------------------------------------------
__global__ void __launch_bounds__(256) fixup_kernel(
    const float* __restrict__ obs,
    const float* __restrict__ W0, const float* __restrict__ B0,
    const float* __restrict__ W1, const float* __restrict__ B1,
    const float* __restrict__ W2, const float* __restrict__ B2,
    const float* __restrict__ cb, const double* __restrict__ n64,
    const int* __restrict__ fcnt, const int* __restrict__ flist,
    int* __restrict__ idxbuf)
{
    __shared__ double h0s[HD];
    __shared__ double h1s[HD];
    __shared__ double ep[16][17];
    __shared__ double es[CD];
    __shared__ double dmin[256];
    __shared__ int    imin[256];

    int n = *fcnt;
    if (n > BATCH * OBS) n = BATCH * OBS;
    const int j = threadIdx.x;

    for (int f = blockIdx.x; f < n; f += gridDim.x) {
        const int T = flist[f];
        const int b = T >> 5, t = T & 31;
        const double x = (double)obs[b * OBS + t];
        {
            double a = fma(x, (double)W0[j], (double)W0[(1 + t) * HD + j])
                     + (double)B0[j];
            h0s[j] = a > 0.0 ? a : 0.0;
        }
        __syncthreads();
        {
            double s = 0.0;
            for (int k = 0; k < HD; ++k)
                s = fma(h0s[k], (double)W1[k * HD + j], s);
            s += (double)B1[j];
            h1s[j] = s > 0.0 ? s : 0.0;
        }
        __syncthreads();
        {
            const int d = j & 15, part = j >> 4;
            double s = 0.0;
            for (int k = part * 16; k < part * 16 + 16; ++k)
                s = fma(h1s[k], (double)W2[k * CD + d], s);
            ep[part][d] = s;
        }
        __syncthreads();
        if (j < CD) {
            double s = 0.0;
            for (int p = 0; p < 16; ++p) s += ep[p][j];
            es[j] = s + (double)B2[j];
        }
        __syncthreads();
        {
            double best = 1e300; int bi = 0x7fffffff;
            for (int c = j; c < NC; c += 256) {
                double dot = 0.0;
                #pragma unroll
                for (int qq = 0; qq < CD; ++qq)
                    dot = fma(es[qq], (double)cb[c * CD + qq], dot);
                double D = n64[c] - 2.0 * dot;
                if (D < best || (D == best && c < bi)) { best = D; bi = c; }
            }
            dmin[j] = best; imin[j] = bi;
        }
        __syncthreads();
        if (j == 0) {
            double best = dmin[0]; int bi = imin[0];
            for (int k = 1; k < 256; ++k)
                if (dmin[k] < best || (dmin[k] == best && imin[k] < bi)) {
                    best = dmin[k]; bi = imin[k];
                }
            idxbuf[T] = bi;
        }
        __syncthreads();
    }
}

// ---------------------------------------------------------------------------
// Kernel 3: decoder MLP 512 -> 256 -> 256 -> 32, 16 batch rows per block
// (round-4 measured config — do not restructure: absmax 0.0 depends on the
// exact fp32 accumulation order).
// ---------------------------------------------------------------------------
__global__ void __launch_bounds__(256) decoder_kernel(
    const int* __restrict__ idx, const float* __restrict__ cbk,
    const float* __restrict__ W0, const float* __restrict__ B0,
    const float* __restrict__ W1, const float* __restrict__ B1,
    const float* __restrict__ W2, const float* __restrict__ B2,
    float* __restrict__ out)
{
    __shared__ float qb[16][512];
    __shared__ float hb[16][256];
    const int tid = threadIdx.x;
    const int row0 = blockIdx.x * 16;

    {
        const int base = row0 * OBS;
        #pragma unroll
        for (int m = 0; m < 2; ++m) {
            int g = tid * 2 + m;
            int ciq = idx[base + g];
            const float4* src = (const float4*)(cbk + ciq * CD);
            float4* dst = (float4*)&qb[g >> 5][(g & 31) * CD];
            dst[0] = src[0]; dst[1] = src[1]; dst[2] = src[2]; dst[3] = src[3];
        }
    }
    __syncthreads();

    const int jg = tid & 63, tg = tid >> 6;
    const int j0 = jg * 4, r0 = tg * 4;

    {
        float acA[4][4], acB[4][4];
        #pragma unroll
        for (int tt = 0; tt < 4; ++tt)
            #pragma unroll
            for (int u = 0; u < 4; ++u) { acA[tt][u] = 0.f; acB[tt][u] = 0.f; }
        for (int k = 0; k < 512; k += 4) {
            float hr[4][4];
            #pragma unroll
            for (int tt = 0; tt < 4; ++tt) {
                float4 hv = *(const float4*)&qb[r0 + tt][k];
                hr[tt][0] = hv.x; hr[tt][1] = hv.y; hr[tt][2] = hv.z; hr[tt][3] = hv.w;
            }
            #pragma unroll
            for (int p = 0; p < 4; ++p) {
                float4 w = *(const float4*)(W0 + (k + p) * 256 + j0);
                if (p < 2) {
                    #pragma unroll
                    for (int tt = 0; tt < 4; ++tt) {
                        acA[tt][0] = fmaf(hr[tt][p], w.x, acA[tt][0]);
                        acA[tt][1] = fmaf(hr[tt][p], w.y, acA[tt][1]);
                        acA[tt][2] = fmaf(hr[tt][p], w.z, acA[tt][2]);
                        acA[tt][3] = fmaf(hr[tt][p], w.w, acA[tt][3]);
                    }
                } else {
                    #pragma unroll
                    for (int tt = 0; tt < 4; ++tt) {
                        acB[tt][0] = fmaf(hr[tt][p], w.x, acB[tt][0]);
                        acB[tt][1] = fmaf(hr[tt][p], w.y, acB[tt][1]);
                        acB[tt][2] = fmaf(hr[tt][p], w.z, acB[tt][2]);
                        acB[tt][3] = fmaf(hr[tt][p], w.w, acB[tt][3]);
                    }
                }
            }
        }
        #pragma unroll
        for (int tt = 0; tt < 4; ++tt)
            #pragma unroll
            for (int u = 0; u < 4; ++u)
                hb[r0 + tt][j0 + u] = fmaxf((acA[tt][u] + acB[tt][u]) + B0[j0 + u], 0.f);
    }
    __syncthreads();

    float* h2 = &qb[0][0];
    {
        float acA[4][4], acB[4][4];
        #pragma unroll
        for (int tt = 0; tt < 4; ++tt)
            #pragma unroll
            for (int u = 0; u < 4; ++u) { acA[tt][u] = 0.f; acB[tt][u] = 0.f; }
        for (int k = 0; k < 256; k += 4) {
            float hr[4][4];
            #pragma unroll
            for (int tt = 0; tt < 4; ++tt) {
                float4 hv = *(const float4*)&hb[r0 + tt][k];
                hr[tt][0] = hv.x; hr[tt][1] = hv.y; hr[tt][2] = hv.z; hr[tt][3] = hv.w;
            }
            #pragma unroll
            for (int p = 0; p < 4; ++p) {
                float4 w = *(const float4*)(W1 + (k + p) * 256 + j0);
                if (p < 2) {
                    #pragma unroll
                    for (int tt = 0; tt < 4; ++tt) {
                        acA[tt][0] = fmaf(hr[tt][p], w.x, acA[tt][0]);
                        acA[tt][1] = fmaf(hr[tt][p], w.y, acA[tt][1]);
                        acA[tt][2] = fmaf(hr[tt][p], w.z, acA[tt][2]);
                        acA[tt][3] = fmaf(hr[tt][p], w.w, acA[tt][3]);
                    }
                } else {
                    #pragma unroll
                    for (int tt = 0; tt < 4; ++tt) {
                        acB[tt][0] = fmaf(hr[tt][p], w.x, acB[tt][0]);
                        acB[tt][1] = fmaf(hr[tt][p], w.y, acB[tt][1]);
                        acB[tt][2] = fmaf(hr[tt][p], w.z, acB[tt][2]);
                        acB[tt][3] = fmaf(hr[tt][p], w.w, acB[tt][3]);
                    }
                }
            }
        }
        __syncthreads();
        #pragma unroll
        for (int tt = 0; tt < 4; ++tt)
            #pragma unroll
            for (int u = 0; u < 4; ++u)
                h2[(r0 + tt) * 256 + j0 + u] =
                    fmaxf((acA[tt][u] + acB[tt][u]) + B1[j0 + u], 0.f);
    }
    __syncthreads();

    {
        const int c  = tid & 31;
        const int rg = tid >> 5;
        for (int rr = rg; rr < 16; rr += 8) {
            float a0 = 0.f, a1 = 0.f, a2 = 0.f, a3 = 0.f;
            #pragma unroll 4
            for (int k = 0; k < 256; k += 4) {
                float4 hv = *(const float4*)&h2[rr * 256 + k];
                a0 = fmaf(hv.x, W2[(k + 0) * 32 + c], a0);
                a1 = fmaf(hv.y, W2[(k + 1) * 32 + c], a1);
                a2 = fmaf(hv.z, W2[(k + 2) * 32 + c], a2);
                a3 = fmaf(hv.w, W2[(k + 3) * 32 + c], a3);
            }
            out[(row0 + rr) * 32 + c] = ((a0 + a1) + (a2 + a3)) + B2[c];
        }
    }
}

// ---------------------------------------------------------------------------
extern "C" void kernel_launch(void* const* d_in, const int* in_sizes, int n_in,
                              void* d_out, int out_size, void* d_ws, size_t ws_size,
                              hipStream_t stream) {
    (void)in_sizes; (void)n_in; (void)out_size; (void)ws_size;
    const float* obs = (const float*)d_in[0];
    const float* eW0 = (const float*)d_in[1];
    const float* eb0 = (const float*)d_in[2];
    const float* eW1 = (const float*)d_in[3];
    const float* eb1 = (const float*)d_in[4];
    const float* eW2 = (const float*)d_in[5];
    const float* eb2 = (const float*)d_in[6];
    const float* dW0 = (const float*)d_in[7];
    const float* db0 = (const float*)d_in[8];
    const float* dW1 = (const float*)d_in[9];
    const float* db1 = (const float*)d_in[10];
    const float* dW2 = (const float*)d_in[11];
    const float* db2 = (const float*)d_in[12];
    const float* cb  = (const float*)d_in[13];

    char*   ws    = (char*)d_ws;
    float*  n32   = (float*)ws;                          // 2 KB
    double* n64   = (double*)(ws + 4096);                // 4 KB
    int*    fcnt  = (int*)(ws + 8192);                   // 4 B
    int*    flist = (int*)(ws + 8448);                   // 1 MB
    int*    idxb  = (int*)(ws + 8448 + 1048576);         // 1 MB (ends 2105600)
    float*  w0m   = (float*)(ws + 3145728);              // 32 KB (gap before wsW1)
    u16*    wsW1  = (u16*)(ws + 4194304);                // 256 KB
    u16*    wsW2  = (u16*)(ws + 4194304 + 262144);       // 16.5 KB (pad 32 KB)
    u16*    wsCB  = (u16*)(ws + 4194304 + 262144 + 32768); // 64 KB

    prep_kernel<<<260, 256, 0, stream>>>(cb, eW1, eW2, eW0, eb0, n32, n64, fcnt,
                                         wsW1, wsW2, wsCB, w0m);
    encoder_kernel<<<BATCH / 2, 256, 0, stream>>>(obs, eW0, w0m, eb1, eb2,
                                                  wsW1, wsW2, wsCB, n32,
                                                  idxb, fcnt, flist);
    fixup_kernel<<<256, 256, 0, stream>>>(obs, eW0, eb0, eW1, eb1, eW2, eb2,
                                          cb, n64, fcnt, flist, idxb);
    decoder_kernel<<<BATCH / 16, 256, 0, stream>>>(idxb, cb, dW0, db0, dW1, db1,
                                                   dW2, db2, (float*)d_out);
}